// Round 11
// baseline (259.499 us; speedup 1.0000x reference)
//
#include <hip/hip_runtime.h>
#include <stdint.h>

// Problem constants (fixed by setup_inputs)
#define N_IMG 4
#define E_DIM 16
#define H_DIM 768
#define W_DIM 768
#define P_PIX (H_DIM * W_DIM)   // 589824 pixels per image
#define C_CL 32

#define DELTA_VAR 0.5f
#define DELTA_DIST 2.0f
#define GAMMA_W 0.001f
#define EPS_F 1e-12f

// Workspace layout (floats):
//   [0,    2048): sums   [N][C][E]        (c*16+e)
//   [2048, 2176): counts [N][C]
//   [2176, 4480): pass2 per-block hinge partials [N][BLOCKS2_X] (big/mid path)
//                 (fallback: scalar hinge per image at [2176, 2180))
//   [4480, ...) : pass1 per-block partials [N][576][544]    (big path)
#define WS_SUMS 0
#define WS_CNT 2048
#define WS_HINGE 2176
#define WS_HP 2176
#define WS_PART 4480
#define PART_STRIDE 544   // 512 sums + 32 counts per block
#define NPART_FLOATS (N_IMG * 576 * PART_STRIDE)

// Pass 1 geometry: 576 blocks/img x 4 waves x 256 px/wave = 589824 px exactly.
#define P1_BLOCKS 576
#define P1_TILES 8              // 8 tiles of 32 px per wave

// Pass 2 geometry: 2048 px/block (2 windows of 1024), 1152 blocks.
#define PX2 2048
#define BLOCKS2_X (P_PIX / PX2) // 288

using bf16x8 = __attribute__((ext_vector_type(8))) short;
using f32x4 = __attribute__((ext_vector_type(4))) float;

__device__ __forceinline__ void gatomic_add(float* p, float v) {
#if defined(__HIP_DEVICE_COMPILE__)
  unsafeAtomicAdd(p, v);  // hw global_atomic_add_f32 on gfx950
#else
  atomicAdd(p, v);
#endif
}

// Pass 1: segment-sum as MFMA. sums[e][c] = sum_p v[e][p] * onehot[p][c].
// HW-verified (rounds 4/7/10, passed). Store-flush of per-block partials
// (round-4 rocprof: 1.18M device-scope atomics into ~36 lines serialized at
// the coherence point; WRITE_SIZE 18.7MB vs 4.7MB logical).
// UNCHANGED this round for attribution (only pass2 modified).
__global__ __launch_bounds__(256) void pass1(const float* __restrict__ input,
                                             const int* __restrict__ target,
                                             float* __restrict__ ws,
                                             int partmode) {
  __shared__ float s_red[4][2][4][64];  // wave, c-half, reg, lane : 8 KB
  __shared__ float s_cnt[4][2][16];
  const int tid = threadIdx.x;
  const int wv = tid >> 6, l = tid & 63;
  const int g = l >> 4, cl = l & 15;  // k-group, and (e-row for A / c-col for B)
  const int n = blockIdx.y;

  const int wid = blockIdx.x * 4 + wv;          // 0..2303 per image
  const int base = wid * (P1_TILES * 32) + g * 8;
  const float* rowp = input + ((size_t)n * E_DIM + cl) * P_PIX;
  const int* tgt = target + (size_t)n * P_PIX;

  f32x4 acc0 = {0.f, 0.f, 0.f, 0.f}, acc1 = {0.f, 0.f, 0.f, 0.f};
  f32x4 cnt0 = {0.f, 0.f, 0.f, 0.f}, cnt1 = {0.f, 0.f, 0.f, 0.f};
  const short ONE = (short)0x3F80;  // bf16 1.0
  const bf16x8 ones = {ONE, ONE, ONE, ONE, ONE, ONE, ONE, ONE};

  // software pipeline, distance 1
  float4 va = *reinterpret_cast<const float4*>(rowp + base);
  float4 vb = *reinterpret_cast<const float4*>(rowp + base + 4);
  int4 la = *reinterpret_cast<const int4*>(tgt + base);
  int4 lb = *reinterpret_cast<const int4*>(tgt + base + 4);

  for (int t = 0; t < P1_TILES; ++t) {
    const float4 cva = va, cvb = vb;
    const int4 cla = la, clb = lb;
    if (t + 1 < P1_TILES) {
      const int p = base + (t + 1) * 32;
      va = *reinterpret_cast<const float4*>(rowp + p);
      vb = *reinterpret_cast<const float4*>(rowp + p + 4);
      la = *reinterpret_cast<const int4*>(tgt + p);
      lb = *reinterpret_cast<const int4*>(tgt + p + 4);
    }

    float ff[8];
    ff[0] = cva.x; ff[1] = cva.y; ff[2] = cva.z; ff[3] = cva.w;
    ff[4] = cvb.x; ff[5] = cvb.y; ff[6] = cvb.z; ff[7] = cvb.w;
    int lab[8];
    lab[0] = cla.x; lab[1] = cla.y; lab[2] = cla.z; lab[3] = cla.w;
    lab[4] = clb.x; lab[5] = clb.y; lab[6] = clb.z; lab[7] = clb.w;

    // A fragments: hi = truncate-to-bf16, lo = bf16(v - hi). Exact split:
    // total representation error ~2^-16 relative.
    union BF { uint32_t w[4]; bf16x8 v; } Ahi, Alo, B0, B1;
#pragma unroll
    for (int q = 0; q < 4; ++q) {
      const uint32_t u0 = __float_as_uint(ff[2 * q]);
      const uint32_t u1 = __float_as_uint(ff[2 * q + 1]);
      Ahi.w[q] = (u0 >> 16) | (u1 & 0xFFFF0000u);
      const float r0 = ff[2 * q] - __uint_as_float(u0 & 0xFFFF0000u);
      const float r1 = ff[2 * q + 1] - __uint_as_float(u1 & 0xFFFF0000u);
      Alo.w[q] = (__float_as_uint(r0) >> 16) | (__float_as_uint(r1) & 0xFFFF0000u);
      // B one-hot fragments for cluster columns cl (half 0) and cl+16 (half 1)
      B0.w[q] = ((lab[2 * q] == cl) ? 0x3F80u : 0u) |
                ((lab[2 * q + 1] == cl) ? 0x3F800000u : 0u);
      B1.w[q] = ((lab[2 * q] == cl + 16) ? 0x3F80u : 0u) |
                ((lab[2 * q + 1] == cl + 16) ? 0x3F800000u : 0u);
    }

    acc0 = __builtin_amdgcn_mfma_f32_16x16x32_bf16(Ahi.v, B0.v, acc0, 0, 0, 0);
    acc0 = __builtin_amdgcn_mfma_f32_16x16x32_bf16(Alo.v, B0.v, acc0, 0, 0, 0);
    acc1 = __builtin_amdgcn_mfma_f32_16x16x32_bf16(Ahi.v, B1.v, acc1, 0, 0, 0);
    acc1 = __builtin_amdgcn_mfma_f32_16x16x32_bf16(Alo.v, B1.v, acc1, 0, 0, 0);
    cnt0 = __builtin_amdgcn_mfma_f32_16x16x32_bf16(ones, B0.v, cnt0, 0, 0, 0);
    cnt1 = __builtin_amdgcn_mfma_f32_16x16x32_bf16(ones, B1.v, cnt1, 0, 0, 0);
  }

  // Block reduction (8 KB LDS).
#pragma unroll
  for (int r = 0; r < 4; ++r) {
    s_red[wv][0][r][l] = acc0[r];
    s_red[wv][1][r][l] = acc1[r];
  }
  if (g == 0) {  // D row 0 holds the counts
    s_cnt[wv][0][cl] = cnt0[0];
    s_cnt[wv][1][cl] = cnt1[0];
  }
  __syncthreads();

  if (partmode) {
    // Contention-free flush: plain stores to this block's private slot.
    float* pbase = ws + WS_PART +
                   (size_t)(n * P1_BLOCKS + blockIdx.x) * PART_STRIDE;
#pragma unroll
    for (int i = tid; i < 512; i += 256) {
      const int h = i >> 8, r = (i >> 6) & 3, ll = i & 63;
      const float v = s_red[0][h][r][ll] + s_red[1][h][r][ll] +
                      s_red[2][h][r][ll] + s_red[3][h][r][ll];
      const int c = (ll & 15) + 16 * h;   // D col = lane&15 (+ half offset)
      const int e = (ll >> 4) * 4 + r;    // D row = (lane>>4)*4 + reg
      pbase[c * E_DIM + e] = v;
    }
    if (tid < C_CL) {
      const int h = tid >> 4, c16 = tid & 15;
      pbase[512 + tid] = s_cnt[0][h][c16] + s_cnt[1][h][c16] +
                         s_cnt[2][h][c16] + s_cnt[3][h][c16];
    }
  } else {
    // Fallback (small ws): original atomic flush (HW-verified).
    float* gsum = ws + WS_SUMS + n * C_CL * E_DIM;
#pragma unroll
    for (int i = tid; i < 512; i += 256) {
      const int h = i >> 8, r = (i >> 6) & 3, ll = i & 63;
      const float v = s_red[0][h][r][ll] + s_red[1][h][r][ll] +
                      s_red[2][h][r][ll] + s_red[3][h][r][ll];
      const int c = (ll & 15) + 16 * h;
      const int e = (ll >> 4) * 4 + r;
      gatomic_add(&gsum[c * E_DIM + e], v);
    }
    if (tid < C_CL) {
      const int h = tid >> 4, c16 = tid & 15;
      const float v = s_cnt[0][h][c16] + s_cnt[1][h][c16] + s_cnt[2][h][c16] +
                      s_cnt[3][h][c16];
      gatomic_add(ws + WS_CNT + n * C_CL + tid, v);
    }
  }
}

// Reduce pass1 partials: sums[n][i] = sum_b part[n][b][i]. grid (17, N_IMG),
// 256 threads = 8 b-subgroups x 32 i-lanes; 17*32 = 544 outputs per image.
__global__ __launch_bounds__(256) void reduce1(float* __restrict__ ws) {
  __shared__ float s[8][32];
  const int tid = threadIdx.x;
  const int bs = tid >> 5, il = tid & 31;
  const int n = blockIdx.y;
  const int i = blockIdx.x * 32 + il;  // [0, 544)
  const float* part = ws + WS_PART + (size_t)n * P1_BLOCKS * PART_STRIDE;
  float acc = 0.f;
#pragma unroll 8
  for (int b = bs; b < P1_BLOCKS; b += 8) acc += part[b * PART_STRIDE + i];
  s[bs][il] = acc;
  __syncthreads();
  if (tid < 32) {
    const int ii = blockIdx.x * 32 + tid;
    float t = s[0][tid] + s[1][tid] + s[2][tid] + s[3][tid] + s[4][tid] +
              s[5][tid] + s[6][tid] + s[7][tid];
    if (ii < 512)
      ws[WS_SUMS + n * 512 + ii] = t;
    else
      ws[WS_CNT + n * C_CL + (ii - 512)] = t;
  }
}

// Pass 2 v3: LINEAR-STREAM restructure.
// Post-mortem r10: TLP/b128 micro-opts were NEUTRAL; pass1 and pass2 both sit
// ~3x above the 25us HBM floor at ~2 TB/s effective -> shared memory-system
// limiter. Theory: 16 input planes (2.36 MB stride) walked INTERLEAVED per
// wave => thousands of open strided streams chip-wide vs the fill's single
// linear stream at 6.9 TB/s. Fix: e-loop OUTER; per e-step each wave issues
// fully-dense contiguous 1KB loads; a block streams 16 sequential 8KB runs
// (one per row) instead of 16 interleaved ones.
// Thread t: 4 px at pA=blk*2048+t*4 (window A) + 4 px at pA+1024 (window B);
// per-pixel d^2 accumulates across e in registers. Mean table TRANSPOSED
// [e][c]: gather addr bank == label -> conflict-free, duplicates broadcast.
__global__ __launch_bounds__(256) void pass2(const float* __restrict__ input,
                                             const int* __restrict__ target,
                                             float* __restrict__ ws,
                                             int hmode) {
  __shared__ float s_meanT[E_DIM][C_CL];  // [e][c]
  __shared__ float s_icnt[C_CL];
  __shared__ float s_part[4];
  const int tid = threadIdx.x;
  const int n = blockIdx.y;
  const float* gsum = ws + WS_SUMS + n * C_CL * E_DIM;
  const float* gcnt = ws + WS_CNT + n * C_CL;
  for (int i = tid; i < C_CL * E_DIM; i += 256) {
    const int c = i >> 4, e = i & 15;
    s_meanT[e][c] = gsum[i] / gcnt[c];
  }
  if (tid < C_CL) s_icnt[tid] = 1.0f / gcnt[tid];
  __syncthreads();

  const int pA = blockIdx.x * PX2 + tid * 4;
  const int pB = pA + 1024;
  const float* inp_n = input + (size_t)n * E_DIM * P_PIX;
  const int* tgt_n = target + (size_t)n * P_PIX;

  const int4 labA = *reinterpret_cast<const int4*>(tgt_n + pA);
  const int4 labB = *reinterpret_cast<const int4*>(tgt_n + pB);

  float aA0 = 0.f, aA1 = 0.f, aA2 = 0.f, aA3 = 0.f;
  float aB0 = 0.f, aB1 = 0.f, aB2 = 0.f, aB3 = 0.f;

#pragma unroll
  for (int e = 0; e < E_DIM; ++e) {
    const float* row = inp_n + (size_t)e * P_PIX;
    const float4 vA = *reinterpret_cast<const float4*>(row + pA);
    const float4 vB = *reinterpret_cast<const float4*>(row + pB);
    const float mA0 = s_meanT[e][labA.x];
    const float mA1 = s_meanT[e][labA.y];
    const float mA2 = s_meanT[e][labA.z];
    const float mA3 = s_meanT[e][labA.w];
    const float mB0 = s_meanT[e][labB.x];
    const float mB1 = s_meanT[e][labB.y];
    const float mB2 = s_meanT[e][labB.z];
    const float mB3 = s_meanT[e][labB.w];
    float d;
    d = vA.x - mA0; aA0 += d * d;
    d = vA.y - mA1; aA1 += d * d;
    d = vA.z - mA2; aA2 += d * d;
    d = vA.w - mA3; aA3 += d * d;
    d = vB.x - mB0; aB0 += d * d;
    d = vB.y - mB1; aB1 += d * d;
    d = vB.z - mB2; aB2 += d * d;
    d = vB.w - mB3; aB3 += d * d;
  }

  float dd, h, acc = 0.f;
  dd = sqrtf(fmaxf(aA0, EPS_F)); h = fmaxf(dd - DELTA_VAR, 0.f);
  acc += h * h * s_icnt[labA.x];
  dd = sqrtf(fmaxf(aA1, EPS_F)); h = fmaxf(dd - DELTA_VAR, 0.f);
  acc += h * h * s_icnt[labA.y];
  dd = sqrtf(fmaxf(aA2, EPS_F)); h = fmaxf(dd - DELTA_VAR, 0.f);
  acc += h * h * s_icnt[labA.z];
  dd = sqrtf(fmaxf(aA3, EPS_F)); h = fmaxf(dd - DELTA_VAR, 0.f);
  acc += h * h * s_icnt[labA.w];
  dd = sqrtf(fmaxf(aB0, EPS_F)); h = fmaxf(dd - DELTA_VAR, 0.f);
  acc += h * h * s_icnt[labB.x];
  dd = sqrtf(fmaxf(aB1, EPS_F)); h = fmaxf(dd - DELTA_VAR, 0.f);
  acc += h * h * s_icnt[labB.y];
  dd = sqrtf(fmaxf(aB2, EPS_F)); h = fmaxf(dd - DELTA_VAR, 0.f);
  acc += h * h * s_icnt[labB.z];
  dd = sqrtf(fmaxf(aB3, EPS_F)); h = fmaxf(dd - DELTA_VAR, 0.f);
  acc += h * h * s_icnt[labB.w];

  // wave shuffle-reduce -> per-wave partial -> one store (or atomic) per block
#pragma unroll
  for (int off = 32; off > 0; off >>= 1) acc += __shfl_down(acc, off);
  if ((tid & 63) == 0) s_part[tid >> 6] = acc;
  __syncthreads();
  if (tid == 0) {
    const float total = s_part[0] + s_part[1] + s_part[2] + s_part[3];
    if (hmode)
      ws[WS_HP + n * BLOCKS2_X + blockIdx.x] = total;
    else
      gatomic_add(ws + WS_HINGE + n, total);
  }
}

// Finalize: variance term + pairwise distance term + regularizer -> scalar.
__global__ __launch_bounds__(256) void finalize(const float* __restrict__ ws,
                                                float* __restrict__ out,
                                                int hmode) {
  __shared__ float s_mean[N_IMG * C_CL * E_DIM];  // 2048 floats
  __shared__ float red[256];
  const int tid = threadIdx.x;
  for (int i = tid; i < N_IMG * C_CL * E_DIM; i += 256) {
    s_mean[i] = ws[WS_SUMS + i] / ws[WS_CNT + (i >> 4)];
  }
  __syncthreads();

  float acc = 0.f;
  // variance term (already sum_p h^2*invcnt per image); apply 1/C
  if (hmode) {
    for (int i = tid; i < N_IMG * BLOCKS2_X; i += 256)
      acc += ws[WS_HP + i] * (1.0f / C_CL);
  } else {
    if (tid < N_IMG) acc += ws[WS_HINGE + tid] * (1.0f / C_CL);
  }
  // regularizer over all (n,c) means
  for (int i = tid; i < N_IMG * C_CL; i += 256) {
    float nrm2 = 0.f;
    const float* m = s_mean + i * E_DIM;
#pragma unroll
    for (int e = 0; e < E_DIM; ++e) nrm2 += m[e] * m[e];
    acc += GAMMA_W * sqrtf(fmaxf(nrm2, EPS_F)) * (1.0f / C_CL);
  }
  for (int t = tid; t < N_IMG * C_CL * C_CL; t += 256) {
    const int n = t / (C_CL * C_CL);
    const int r = t - n * C_CL * C_CL;
    const int a = r >> 5, b = r & 31;
    if (a != b) {
      const float* ma = s_mean + (n * C_CL + a) * E_DIM;
      const float* mb = s_mean + (n * C_CL + b) * E_DIM;
      float d2 = 0.f;
#pragma unroll
      for (int e = 0; e < E_DIM; ++e) {
        const float df = ma[e] - mb[e];
        d2 += df * df;
      }
      const float dist = sqrtf(fmaxf(d2, EPS_F));
      const float hd = fmaxf(2.f * DELTA_DIST - dist, 0.f);
      acc += hd * hd * (1.0f / (C_CL * (C_CL - 1)));
    }
  }

  red[tid] = acc;
  __syncthreads();
  for (int s = 128; s > 0; s >>= 1) {
    if (tid < s) red[tid] += red[tid + s];
    __syncthreads();
  }
  if (tid == 0) out[0] = red[0] * (1.0f / N_IMG);
}

extern "C" void kernel_launch(void* const* d_in, const int* in_sizes, int n_in,
                              void* d_out, int out_size, void* d_ws,
                              size_t ws_size, hipStream_t stream) {
  const float* input = (const float*)d_in[0];
  const int* target = (const int*)d_in[1];
  float* ws = (float*)d_ws;
  float* out = (float*)d_out;

  const bool big_ws = ws_size >= (size_t)(WS_PART + NPART_FLOATS) * 4;
  const bool mid_ws = ws_size >= (size_t)WS_PART * 4;
  const int partmode = big_ws ? 1 : 0;
  const int hmode = mid_ws ? 1 : 0;

  if (!big_ws || !mid_ws) {
    hipMemsetAsync(ws, 0, 2180 * sizeof(float), stream);
  }
  dim3 grid1(P1_BLOCKS, N_IMG);
  pass1<<<grid1, 256, 0, stream>>>(input, target, ws, partmode);
  if (big_ws) {
    dim3 gridr(17, N_IMG);
    reduce1<<<gridr, 256, 0, stream>>>(ws);
  }
  dim3 grid2(BLOCKS2_X, N_IMG);
  pass2<<<grid2, 256, 0, stream>>>(input, target, ws, hmode);
  finalize<<<1, 256, 0, stream>>>(ws, out, hmode);
}